// Round 8
// baseline (238.518 us; speedup 1.0000x reference)
//
#include <hip/hip_runtime.h>
#include <hip/hip_bf16.h>
#include <stdint.h>

// Problem: B=8, L=1024, C=1024, H=16, HD=64, window +/-64 (WS=128).
// Model (confirmed): inputs f32, output f32, bf16 intermediates.
// Round-8: attn rewrite — V stored transposed by gemm_qkv (no in-kernel
// scalar transpose), window-exact 9-of-12 key tiles per wave, 5-of-6 PV
// chunks. GEMMs/cast unchanged from round 7.

typedef __attribute__((ext_vector_type(8))) short bf16x8;
typedef __attribute__((ext_vector_type(4))) float f32x4;

__device__ inline unsigned short f2b(float f) {
    __hip_bfloat16 h = __float2bfloat16(f);
    return *reinterpret_cast<unsigned short*>(&h);
}

// async global->LDS, 16B per lane; LDS dest = wave-uniform base + lane*16
__device__ inline void gld16(const unsigned short* g, unsigned short* l) {
    __builtin_amdgcn_global_load_lds(
        (const __attribute__((address_space(1))) void*)g,
        (__attribute__((address_space(3))) void*)l, 16, 0, 0);
}

#define BM 128
#define BN 128
#define BK 64

// ---- cast f32 inputs to bf16 side buffers (x, in_proj_w, out_w) ----
__global__ void __launch_bounds__(256) cast_inputs(
    const float4* __restrict__ x, const float4* __restrict__ w1,
    const float4* __restrict__ w2,
    uint2* __restrict__ xb, uint2* __restrict__ w1b, uint2* __restrict__ w2b)
{
    const int N0 = 2097152, N1 = 786432, N2 = 262144;  // float4 counts
    int stride = gridDim.x * blockDim.x;
    for (int i = blockIdx.x * blockDim.x + threadIdx.x; i < N0 + N1 + N2; i += stride) {
        const float4* src; uint2* dst; int idx;
        if (i < N0)            { src = x;  dst = xb;  idx = i; }
        else if (i < N0 + N1)  { src = w1; dst = w1b; idx = i - N0; }
        else                   { src = w2; dst = w2b; idx = i - N0 - N1; }
        float4 f = src[idx];
        unsigned short t[4] = {f2b(f.x), f2b(f.y), f2b(f.z), f2b(f.w)};
        dst[idx] = *(uint2*)t;
    }
}

// ---- QKV GEMM: C[M,N] = xb[M,K] * w1b[N,K]^T + b1 ----
// Q,K scattered as [bh][sl][d]; V scattered TRANSPOSED as [bh][d][sl].
__global__ void __launch_bounds__(256) gemm_qkv(
    const unsigned short* __restrict__ A,   // xb [8192,1024] bf16
    const unsigned short* __restrict__ W,   // w1b [3072,1024] bf16
    const float* __restrict__ bias,         // [3072] f32
    unsigned short* __restrict__ Qo,
    unsigned short* __restrict__ Ko,
    unsigned short* __restrict__ Vo)        // V^T [128][64][1024]
{
    const int K = 1024;
    int n0 = blockIdx.x * BN;
    int m0 = blockIdx.y * BM;
    int tid = threadIdx.x;
    int wave = tid >> 6, lane = tid & 63;
    int lm = lane & 15, quad = lane >> 4;
    int mblk = (wave & 1) * 64, nblk = (wave >> 1) * 64;

    __shared__ unsigned short As[BM * BK];  // 16 KiB
    __shared__ unsigned short Bs[BN * BK];  // 16 KiB

    int drow = lane >> 3;               // 0..7 row within an 8-row DMA chunk
    int gcc  = (lane & 7) ^ drow;       // swizzled logical col-chunk (x8 elems)
    const unsigned short* ga[4]; const unsigned short* gb[4];
    unsigned short *la[4], *lb[4];
#pragma unroll
    for (int p = 0; p < 4; ++p) {
        int r = wave * 32 + p * 8 + drow;
        ga[p] = A + (size_t)(m0 + r) * K + gcc * 8;
        gb[p] = W + (size_t)(n0 + r) * K + gcc * 8;
        la[p] = As + (wave * 32 + p * 8) * 64;
        lb[p] = Bs + (wave * 32 + p * 8) * 64;
    }
    int lm7 = lm & 7;

    f32x4 acc[4][4];
#pragma unroll
    for (int i = 0; i < 4; ++i)
#pragma unroll
        for (int j = 0; j < 4; ++j)
            acc[i][j] = (f32x4){0.f, 0.f, 0.f, 0.f};

    for (int k0 = 0; k0 < K; k0 += BK) {
        __syncthreads();
#pragma unroll
        for (int p = 0; p < 4; ++p) gld16(ga[p] + k0, la[p]);
#pragma unroll
        for (int p = 0; p < 4; ++p) gld16(gb[p] + k0, lb[p]);
        __syncthreads();
        bf16x8 af[4][2], bfr[4][2];
#pragma unroll
        for (int i = 0; i < 4; ++i)
#pragma unroll
            for (int hhh = 0; hhh < 2; ++hhh)
                af[i][hhh] = *(const bf16x8*)(As + (mblk + i * 16 + lm) * 64 +
                                              (((hhh * 4 + quad) ^ lm7) << 3));
#pragma unroll
        for (int j = 0; j < 4; ++j)
#pragma unroll
            for (int hhh = 0; hhh < 2; ++hhh)
                bfr[j][hhh] = *(const bf16x8*)(Bs + (nblk + j * 16 + lm) * 64 +
                                               (((hhh * 4 + quad) ^ lm7) << 3));
#pragma unroll
        for (int i = 0; i < 4; ++i)
#pragma unroll
            for (int j = 0; j < 4; ++j) {
                acc[i][j] = __builtin_amdgcn_mfma_f32_16x16x32_bf16(af[i][0], bfr[j][0], acc[i][j], 0, 0, 0);
                acc[i][j] = __builtin_amdgcn_mfma_f32_16x16x32_bf16(af[i][1], bfr[j][1], acc[i][j], 0, 0, 0);
            }
    }

#pragma unroll
    for (int j = 0; j < 4; ++j) {
        int n = n0 + nblk + j * 16 + lm;
        float bv = bias[n];
        int sec = n >> 10, rem = n & 1023;
        int h = rem >> 6, d = rem & 63;
#pragma unroll
        for (int i = 0; i < 4; ++i) {
#pragma unroll
            for (int r = 0; r < 4; ++r) {
                int m = m0 + mblk + i * 16 + quad * 4 + r;
                int bb = m >> 10, sl = m & 1023;
                int bh = bb * 16 + h;
                unsigned short val = f2b(acc[i][j][r] + bv);
                if (sec == 0)
                    Qo[((size_t)bh * 1024 + sl) * 64 + d] = val;
                else if (sec == 1)
                    Ko[((size_t)bh * 1024 + sl) * 64 + d] = val;
                else
                    Vo[((size_t)bh * 64 + d) * 1024 + sl] = val;  // transposed
            }
        }
    }
}

// ---- local attention ----
// One block per (b,h,64-row q tile). Keys window [q0-64, q0+128) = 192.
// Wave w (q rows [q0+16w,+16)) needs only key tiles [w, w+8] (9 of 12).
__global__ void __launch_bounds__(256) attn_local(
    const unsigned short* __restrict__ Qg,   // [B*H,1024,64] bf16
    const unsigned short* __restrict__ Kg,   // [B*H,1024,64] bf16
    const unsigned short* __restrict__ Vg,   // V^T [B*H,64,1024] bf16
    unsigned short* __restrict__ Og)         // [8192,1024] bf16
{
    const int KP = 72;    // K-tile pitch (64+8)
    const int VP = 200;   // Vt / P pitch (192+8)
    __shared__ unsigned short Ks[192 * KP];  // reused as P after barrier
    __shared__ unsigned short Vt[64 * VP];

    int tid = threadIdx.x;
    int wave = tid >> 6, lane = tid & 63;
    int lm = lane & 15, quad = lane >> 4;

    int bh = blockIdx.x >> 4;
    int qt = blockIdx.x & 15;
    int q0 = qt * 64;
    int b = bh >> 4, h = bh & 15;
    const unsigned short* Qbh = Qg + (size_t)bh * 1024 * 64;
    const unsigned short* Kbh = Kg + (size_t)bh * 1024 * 64;
    const unsigned short* Vbh = Vg + (size_t)bh * 64 * 1024;
    int j0 = q0 - 64;

    // stage K rows: 192 rows x 8 chunks = 1536 uint4
#pragma unroll
    for (int it = 0; it < 6; ++it) {
        int id = it * 256 + tid;
        int r = id >> 3;             // key row 0..191
        int c = (id & 7) * 8;        // d offset
        int j = j0 + r;
        uint4 kv; kv.x = kv.y = kv.z = kv.w = 0;
        if (j >= 0 && j < 1024) kv = *(const uint4*)(Kbh + (size_t)j * 64 + c);
        *(uint4*)(Ks + r * KP + c) = kv;
    }
    // stage V^T rows: 64 rows x 24 chunks = 1536 uint4 (no transpose needed)
#pragma unroll
    for (int it = 0; it < 6; ++it) {
        int id = it * 256 + tid;
        int d = id / 24;             // 0..63
        int c = id - d * 24;         // chunk 0..23
        int j = j0 + c * 8;
        uint4 vv; vv.x = vv.y = vv.z = vv.w = 0;
        if (j >= 0 && j + 7 < 1024) vv = *(const uint4*)(Vbh + (size_t)d * 1024 + j);
        *(uint4*)(Vt + d * VP + c * 8) = vv;
    }
    __syncthreads();

    int qrow = q0 + wave * 16;
    bf16x8 qf0 = *(const bf16x8*)(Qbh + (size_t)(qrow + lm) * 64 + quad * 8);
    bf16x8 qf1 = *(const bf16x8*)(Qbh + (size_t)(qrow + lm) * 64 + 32 + quad * 8);

    // scores: 9 key tiles [wave, wave+8]
    f32x4 sc[9];
#pragma unroll
    for (int kt = 0; kt < 9; ++kt) {
        int akt = wave + kt;
        f32x4 a = (f32x4){0.f, 0.f, 0.f, 0.f};
        bf16x8 k0f = *(const bf16x8*)(Ks + (akt * 16 + lm) * KP + quad * 8);
        bf16x8 k1f = *(const bf16x8*)(Ks + (akt * 16 + lm) * KP + 32 + quad * 8);
        a = __builtin_amdgcn_mfma_f32_16x16x32_bf16(qf0, k0f, a, 0, 0, 0);
        a = __builtin_amdgcn_mfma_f32_16x16x32_bf16(qf1, k1f, a, 0, 0, 0);
        sc[kt] = a;
    }

    float mx[4] = {-3e38f, -3e38f, -3e38f, -3e38f};
#pragma unroll
    for (int kt = 0; kt < 9; ++kt) {
        int jg = j0 + (wave + kt) * 16 + lm;
#pragma unroll
        for (int r = 0; r < 4; ++r) {
            int irow = q0 + wave * 16 + quad * 4 + r;
            int diff = irow - jg;
            bool ok = (jg >= 0) && (jg < 1024) && (diff <= 64) && (diff >= -64);
            float s = ok ? sc[kt][r] * 0.125f : -30000.0f;
            sc[kt][r] = s;
            mx[r] = fmaxf(mx[r], s);
        }
    }
#pragma unroll
    for (int off = 1; off <= 8; off <<= 1)
#pragma unroll
        for (int r = 0; r < 4; ++r)
            mx[r] = fmaxf(mx[r], __shfl_xor(mx[r], off, 64));

    float sum[4] = {0.f, 0.f, 0.f, 0.f};
#pragma unroll
    for (int kt = 0; kt < 9; ++kt)
#pragma unroll
        for (int r = 0; r < 4; ++r) {
            float p = __expf(sc[kt][r] - mx[r]);
            sc[kt][r] = p;
            sum[r] += p;
        }
#pragma unroll
    for (int off = 1; off <= 8; off <<= 1)
#pragma unroll
        for (int r = 0; r < 4; ++r)
            sum[r] += __shfl_xor(sum[r], off, 64);

    __syncthreads();  // done reading Ks as K tile
    unsigned short* Pb = Ks + wave * 3200;  // per-wave P [16][VP]
#pragma unroll
    for (int kt = 0; kt < 9; ++kt) {
        int akt = wave + kt;
#pragma unroll
        for (int r = 0; r < 4; ++r)
            Pb[(quad * 4 + r) * VP + akt * 16 + lm] = f2b(sc[kt][r]);
    }
    // zero the one unwritten tile inside this wave's PV chunk range
    {
        int zkt = (wave & 1) ? (wave - 1) : (wave + 9);
#pragma unroll
        for (int r = 0; r < 4; ++r)
            Pb[(quad * 4 + r) * VP + zkt * 16 + lm] = 0;
    }
    __syncthreads();

    // O[16q][64d] = P[16][..] * V^T ; 5 of 6 32-key chunks cover the window
    int jclo = wave >> 1;
    f32x4 o[4];
#pragma unroll
    for (int n = 0; n < 4; ++n) o[n] = (f32x4){0.f, 0.f, 0.f, 0.f};
#pragma unroll
    for (int jc2 = 0; jc2 < 5; ++jc2) {
        int jc = jclo + jc2;
        bf16x8 pf = *(const bf16x8*)(Pb + lm * VP + jc * 32 + quad * 8);
#pragma unroll
        for (int n = 0; n < 4; ++n) {
            bf16x8 vf = *(const bf16x8*)(Vt + (n * 16 + lm) * VP + jc * 32 + quad * 8);
            o[n] = __builtin_amdgcn_mfma_f32_16x16x32_bf16(pf, vf, o[n], 0, 0, 0);
        }
    }

    float inv[4];
#pragma unroll
    for (int r = 0; r < 4; ++r) inv[r] = 1.0f / sum[r];
#pragma unroll
    for (int n = 0; n < 4; ++n)
#pragma unroll
        for (int r = 0; r < 4; ++r) {
            int orow = q0 + wave * 16 + quad * 4 + r;
            size_t oidx = ((size_t)(b * 1024 + orow)) * 1024 + h * 64 + n * 16 + lm;
            Og[oidx] = f2b(o[n][r] * inv[r]);
        }
}

// ---- proj GEMM: out[M,N] = attn[M,K] * w2b[N,K]^T + b2, f32 out ----
__global__ void __launch_bounds__(256) gemm_proj(
    const unsigned short* __restrict__ A,   // attn [8192,1024] bf16
    const unsigned short* __restrict__ W,   // w2b [1024,1024] bf16
    const float* __restrict__ bias,         // [1024] f32
    float* __restrict__ Out)                // [8192,1024] f32
{
    const int K = 1024;
    int n0 = blockIdx.x * BN;
    int m0 = blockIdx.y * BM;
    int tid = threadIdx.x;
    int wave = tid >> 6, lane = tid & 63;
    int lm = lane & 15, quad = lane >> 4;
    int mblk = (wave & 1) * 64, nblk = (wave >> 1) * 64;

    __shared__ unsigned short As[BM * BK];
    __shared__ unsigned short Bs[BN * BK];

    int drow = lane >> 3;
    int gcc  = (lane & 7) ^ drow;
    const unsigned short* ga[4]; const unsigned short* gb[4];
    unsigned short *la[4], *lb[4];
#pragma unroll
    for (int p = 0; p < 4; ++p) {
        int r = wave * 32 + p * 8 + drow;
        ga[p] = A + (size_t)(m0 + r) * K + gcc * 8;
        gb[p] = W + (size_t)(n0 + r) * K + gcc * 8;
        la[p] = As + (wave * 32 + p * 8) * 64;
        lb[p] = Bs + (wave * 32 + p * 8) * 64;
    }
    int lm7 = lm & 7;

    f32x4 acc[4][4];
#pragma unroll
    for (int i = 0; i < 4; ++i)
#pragma unroll
        for (int j = 0; j < 4; ++j)
            acc[i][j] = (f32x4){0.f, 0.f, 0.f, 0.f};

    for (int k0 = 0; k0 < K; k0 += BK) {
        __syncthreads();
#pragma unroll
        for (int p = 0; p < 4; ++p) gld16(ga[p] + k0, la[p]);
#pragma unroll
        for (int p = 0; p < 4; ++p) gld16(gb[p] + k0, lb[p]);
        __syncthreads();
        bf16x8 af[4][2], bfr[4][2];
#pragma unroll
        for (int i = 0; i < 4; ++i)
#pragma unroll
            for (int hhh = 0; hhh < 2; ++hhh)
                af[i][hhh] = *(const bf16x8*)(As + (mblk + i * 16 + lm) * 64 +
                                              (((hhh * 4 + quad) ^ lm7) << 3));
#pragma unroll
        for (int j = 0; j < 4; ++j)
#pragma unroll
            for (int hhh = 0; hhh < 2; ++hhh)
                bfr[j][hhh] = *(const bf16x8*)(Bs + (nblk + j * 16 + lm) * 64 +
                                               (((hhh * 4 + quad) ^ lm7) << 3));
#pragma unroll
        for (int i = 0; i < 4; ++i)
#pragma unroll
            for (int j = 0; j < 4; ++j) {
                acc[i][j] = __builtin_amdgcn_mfma_f32_16x16x32_bf16(af[i][0], bfr[j][0], acc[i][j], 0, 0, 0);
                acc[i][j] = __builtin_amdgcn_mfma_f32_16x16x32_bf16(af[i][1], bfr[j][1], acc[i][j], 0, 0, 0);
            }
    }

#pragma unroll
    for (int j = 0; j < 4; ++j) {
        int n = n0 + nblk + j * 16 + lm;
        float bv = bias[n];
#pragma unroll
        for (int i = 0; i < 4; ++i) {
#pragma unroll
            for (int r = 0; r < 4; ++r) {
                int m = m0 + mblk + i * 16 + quad * 4 + r;
                Out[(size_t)m * 1024 + n] = acc[i][j][r] + bv;
            }
        }
    }
}

extern "C" void kernel_launch(void* const* d_in, const int* in_sizes, int n_in,
                              void* d_out, int out_size, void* d_ws, size_t ws_size,
                              hipStream_t stream) {
    const float* x  = (const float*)d_in[0];  // [8,1024,1024] f32
    const float* w1 = (const float*)d_in[1];  // [3072,1024] f32
    const float* b1 = (const float*)d_in[2];  // [3072] f32
    const float* w2 = (const float*)d_in[3];  // [1024,1024] f32
    const float* b2 = (const float*)d_in[4];  // [1024] f32
    float* out = (float*)d_out;               // [8192,1024] f32

    // ws (56 MiB peak):
    //  [0,16Mi)   xb  -> overlaid by attn after gemm_qkv
    //  [16,22Mi)  w1b -> dead after gemm_qkv
    //  [22,24Mi)  w2b
    //  [24,40Mi)  q   [40,56Mi) k
    //  v (transposed [128][64][1024]) lives in d_out's first 16 MiB
    char* ws = (char*)d_ws;
    const size_t MB = 1024 * 1024;
    unsigned short* xb   = (unsigned short*)(ws);
    unsigned short* w1b  = (unsigned short*)(ws + 16 * MB);
    unsigned short* w2b  = (unsigned short*)(ws + 22 * MB);
    unsigned short* q    = (unsigned short*)(ws + 24 * MB);
    unsigned short* k    = (unsigned short*)(ws + 40 * MB);
    unsigned short* v    = (unsigned short*)d_out;
    unsigned short* attn = (unsigned short*)(ws);

    dim3 blk(256);
    cast_inputs<<<3072, blk, 0, stream>>>(
        (const float4*)x, (const float4*)w1, (const float4*)w2,
        (uint2*)xb, (uint2*)w1b, (uint2*)w2b);
    gemm_qkv<<<dim3(24, 64), blk, 0, stream>>>(xb, w1b, b1, q, k, v);
    attn_local<<<dim3(2048), blk, 0, stream>>>(q, k, v, attn);
    gemm_proj<<<dim3(8, 64), blk, 0, stream>>>(attn, w2b, b2, out);
}

// Round 9
// 209.623 us; speedup vs baseline: 1.1378x; 1.1378x over previous
//
#include <hip/hip_runtime.h>
#include <hip/hip_bf16.h>
#include <stdint.h>

// Problem: B=8, L=1024, C=1024, H=16, HD=64, window +/-64 (WS=128).
// Model (confirmed): inputs f32, output f32, bf16 intermediates.
// Round-9: revert r8's uncoalesced V^T epilogue (2KB-stride 2B stores cost
// +26us); keep window-exact attn math (proven correct, cost-free); V staged
// row-major with in-kernel LDS transpose (proven cost-neutral in r7/r8 A/B).

typedef __attribute__((ext_vector_type(8))) short bf16x8;
typedef __attribute__((ext_vector_type(4))) float f32x4;

__device__ inline unsigned short f2b(float f) {
    __hip_bfloat16 h = __float2bfloat16(f);
    return *reinterpret_cast<unsigned short*>(&h);
}

// async global->LDS, 16B per lane; LDS dest = wave-uniform base + lane*16
__device__ inline void gld16(const unsigned short* g, unsigned short* l) {
    __builtin_amdgcn_global_load_lds(
        (const __attribute__((address_space(1))) void*)g,
        (__attribute__((address_space(3))) void*)l, 16, 0, 0);
}

#define BM 128
#define BN 128
#define BK 64

// ---- cast f32 inputs to bf16 side buffers: 8 f32 -> one 16B store ----
__global__ void __launch_bounds__(256) cast_inputs(
    const float4* __restrict__ x, const float4* __restrict__ w1,
    const float4* __restrict__ w2,
    uint4* __restrict__ xb, uint4* __restrict__ w1b, uint4* __restrict__ w2b)
{
    const int P0 = 1048576, P1 = 393216, P2 = 131072;  // float4-pair counts
    int stride = gridDim.x * blockDim.x;
    for (int i = blockIdx.x * blockDim.x + threadIdx.x; i < P0 + P1 + P2; i += stride) {
        const float4* src; uint4* dst; int idx;
        if (i < P0)           { src = x;  dst = xb;  idx = i; }
        else if (i < P0 + P1) { src = w1; dst = w1b; idx = i - P0; }
        else                  { src = w2; dst = w2b; idx = i - P0 - P1; }
        float4 a = src[idx * 2], b = src[idx * 2 + 1];
        unsigned short t[8] = {f2b(a.x), f2b(a.y), f2b(a.z), f2b(a.w),
                               f2b(b.x), f2b(b.y), f2b(b.z), f2b(b.w)};
        dst[idx] = *(uint4*)t;
    }
}

// ---- QKV GEMM: C[M,N] = xb[M,K] * w1b[N,K]^T + b1 ; scatter to Q/K/V ----
// 128x64 LDS tiles, XOR swizzle (chunk c of row r at c^(r&7)); DMA staging.
__global__ void __launch_bounds__(256) gemm_qkv(
    const unsigned short* __restrict__ A,   // xb [8192,1024] bf16
    const unsigned short* __restrict__ W,   // w1b [3072,1024] bf16
    const float* __restrict__ bias,         // [3072] f32
    unsigned short* __restrict__ Qo,
    unsigned short* __restrict__ Ko,
    unsigned short* __restrict__ Vo)
{
    const int K = 1024;
    int n0 = blockIdx.x * BN;
    int m0 = blockIdx.y * BM;
    int tid = threadIdx.x;
    int wave = tid >> 6, lane = tid & 63;
    int lm = lane & 15, quad = lane >> 4;
    int mblk = (wave & 1) * 64, nblk = (wave >> 1) * 64;

    __shared__ unsigned short As[BM * BK];  // 16 KiB
    __shared__ unsigned short Bs[BN * BK];  // 16 KiB

    int drow = lane >> 3;               // 0..7 row within an 8-row DMA chunk
    int gcc  = (lane & 7) ^ drow;       // swizzled logical col-chunk (x8 elems)
    const unsigned short* ga[4]; const unsigned short* gb[4];
    unsigned short *la[4], *lb[4];
#pragma unroll
    for (int p = 0; p < 4; ++p) {
        int r = wave * 32 + p * 8 + drow;
        ga[p] = A + (size_t)(m0 + r) * K + gcc * 8;
        gb[p] = W + (size_t)(n0 + r) * K + gcc * 8;
        la[p] = As + (wave * 32 + p * 8) * 64;
        lb[p] = Bs + (wave * 32 + p * 8) * 64;
    }
    int lm7 = lm & 7;

    f32x4 acc[4][4];
#pragma unroll
    for (int i = 0; i < 4; ++i)
#pragma unroll
        for (int j = 0; j < 4; ++j)
            acc[i][j] = (f32x4){0.f, 0.f, 0.f, 0.f};

    for (int k0 = 0; k0 < K; k0 += BK) {
        __syncthreads();                 // prev iter's ds_reads done
#pragma unroll
        for (int p = 0; p < 4; ++p) gld16(ga[p] + k0, la[p]);
#pragma unroll
        for (int p = 0; p < 4; ++p) gld16(gb[p] + k0, lb[p]);
        __syncthreads();                 // DMA drained
        bf16x8 af[4][2], bfr[4][2];
#pragma unroll
        for (int i = 0; i < 4; ++i)
#pragma unroll
            for (int hhh = 0; hhh < 2; ++hhh)
                af[i][hhh] = *(const bf16x8*)(As + (mblk + i * 16 + lm) * 64 +
                                              (((hhh * 4 + quad) ^ lm7) << 3));
#pragma unroll
        for (int j = 0; j < 4; ++j)
#pragma unroll
            for (int hhh = 0; hhh < 2; ++hhh)
                bfr[j][hhh] = *(const bf16x8*)(Bs + (nblk + j * 16 + lm) * 64 +
                                               (((hhh * 4 + quad) ^ lm7) << 3));
#pragma unroll
        for (int i = 0; i < 4; ++i)
#pragma unroll
            for (int j = 0; j < 4; ++j) {
                acc[i][j] = __builtin_amdgcn_mfma_f32_16x16x32_bf16(af[i][0], bfr[j][0], acc[i][j], 0, 0, 0);
                acc[i][j] = __builtin_amdgcn_mfma_f32_16x16x32_bf16(af[i][1], bfr[j][1], acc[i][j], 0, 0, 0);
            }
    }

#pragma unroll
    for (int j = 0; j < 4; ++j) {
        int n = n0 + nblk + j * 16 + lm;
        float bv = bias[n];
        int sec = n >> 10, rem = n & 1023;
        int h = rem >> 6, d = rem & 63;
        unsigned short* dst = (sec == 0) ? Qo : (sec == 1) ? Ko : Vo;
#pragma unroll
        for (int i = 0; i < 4; ++i) {
#pragma unroll
            for (int r = 0; r < 4; ++r) {
                int m = m0 + mblk + i * 16 + quad * 4 + r;
                int bb = m >> 10, sl = m & 1023;
                size_t idx = ((size_t)((bb * 16 + h) * 1024 + sl)) * 64 + d;
                dst[idx] = f2b(acc[i][j][r] + bv);
            }
        }
    }
}

// ---- local attention ----
// One block per (b,h,64-row q tile). Keys window [q0-64, q0+128) = 192.
// Wave w (q rows [q0+16w,+16)) computes only key tiles [w, w+8] (9 of 12)
// and 5 of 6 PV chunks; the one uncovered tile is zeroed in P.
__global__ void __launch_bounds__(256) attn_local(
    const unsigned short* __restrict__ Qg,   // [B*H,1024,64] bf16
    const unsigned short* __restrict__ Kg,   // [B*H,1024,64] bf16
    const unsigned short* __restrict__ Vg,   // [B*H,1024,64] bf16
    unsigned short* __restrict__ Og)         // [8192,1024] bf16
{
    const int KP = 72;    // K-tile pitch (64+8)
    const int VP = 200;   // Vt / P pitch (192+8)
    __shared__ unsigned short Ks[192 * KP];  // reused as P after barrier
    __shared__ unsigned short Vt[64 * VP];

    int tid = threadIdx.x;
    int wave = tid >> 6, lane = tid & 63;
    int lm = lane & 15, quad = lane >> 4;

    int bh = blockIdx.x >> 4;
    int qt = blockIdx.x & 15;
    int q0 = qt * 64;
    int b = bh >> 4, h = bh & 15;
    const unsigned short* Qbh = Qg + (size_t)bh * 1024 * 64;
    const unsigned short* Kbh = Kg + (size_t)bh * 1024 * 64;
    const unsigned short* Vbh = Vg + (size_t)bh * 1024 * 64;
    int j0 = q0 - 64;

    // stage K rows + V^T (scalar transpose; proven cost-neutral)
#pragma unroll
    for (int it = 0; it < 6; ++it) {
        int id = it * 256 + tid;
        int r = id >> 3;             // key row 0..191
        int c = (id & 7) * 8;        // d offset
        int j = j0 + r;
        uint4 kv, vv;
        kv.x = kv.y = kv.z = kv.w = 0;
        vv = kv;
        if (j >= 0 && j < 1024) {
            kv = *(const uint4*)(Kbh + (size_t)j * 64 + c);
            vv = *(const uint4*)(Vbh + (size_t)j * 64 + c);
        }
        *(uint4*)(Ks + r * KP + c) = kv;
        unsigned short tmp[8];
        *(uint4*)tmp = vv;
#pragma unroll
        for (int e = 0; e < 8; ++e) Vt[(c + e) * VP + r] = tmp[e];
    }
    __syncthreads();

    int qrow = q0 + wave * 16;
    bf16x8 qf0 = *(const bf16x8*)(Qbh + (size_t)(qrow + lm) * 64 + quad * 8);
    bf16x8 qf1 = *(const bf16x8*)(Qbh + (size_t)(qrow + lm) * 64 + 32 + quad * 8);

    // scores: 9 key tiles [wave, wave+8]
    f32x4 sc[9];
#pragma unroll
    for (int kt = 0; kt < 9; ++kt) {
        int akt = wave + kt;
        f32x4 a = (f32x4){0.f, 0.f, 0.f, 0.f};
        bf16x8 k0f = *(const bf16x8*)(Ks + (akt * 16 + lm) * KP + quad * 8);
        bf16x8 k1f = *(const bf16x8*)(Ks + (akt * 16 + lm) * KP + 32 + quad * 8);
        a = __builtin_amdgcn_mfma_f32_16x16x32_bf16(qf0, k0f, a, 0, 0, 0);
        a = __builtin_amdgcn_mfma_f32_16x16x32_bf16(qf1, k1f, a, 0, 0, 0);
        sc[kt] = a;
    }

    float mx[4] = {-3e38f, -3e38f, -3e38f, -3e38f};
#pragma unroll
    for (int kt = 0; kt < 9; ++kt) {
        int jg = j0 + (wave + kt) * 16 + lm;
#pragma unroll
        for (int r = 0; r < 4; ++r) {
            int irow = q0 + wave * 16 + quad * 4 + r;
            int diff = irow - jg;
            bool ok = (jg >= 0) && (jg < 1024) && (diff <= 64) && (diff >= -64);
            float s = ok ? sc[kt][r] * 0.125f : -30000.0f;
            sc[kt][r] = s;
            mx[r] = fmaxf(mx[r], s);
        }
    }
#pragma unroll
    for (int off = 1; off <= 8; off <<= 1)
#pragma unroll
        for (int r = 0; r < 4; ++r)
            mx[r] = fmaxf(mx[r], __shfl_xor(mx[r], off, 64));

    float sum[4] = {0.f, 0.f, 0.f, 0.f};
#pragma unroll
    for (int kt = 0; kt < 9; ++kt)
#pragma unroll
        for (int r = 0; r < 4; ++r) {
            float p = __expf(sc[kt][r] - mx[r]);
            sc[kt][r] = p;
            sum[r] += p;
        }
#pragma unroll
    for (int off = 1; off <= 8; off <<= 1)
#pragma unroll
        for (int r = 0; r < 4; ++r)
            sum[r] += __shfl_xor(sum[r], off, 64);

    __syncthreads();  // done reading Ks as K tile
    unsigned short* Pb = Ks + wave * 3200;  // per-wave P [16][VP]
#pragma unroll
    for (int kt = 0; kt < 9; ++kt) {
        int akt = wave + kt;
#pragma unroll
        for (int r = 0; r < 4; ++r)
            Pb[(quad * 4 + r) * VP + akt * 16 + lm] = f2b(sc[kt][r]);
    }
    {   // zero the one tile in this wave's PV range not covered by [w, w+8]
        int zkt = (wave & 1) ? (wave - 1) : (wave + 9);
#pragma unroll
        for (int r = 0; r < 4; ++r)
            Pb[(quad * 4 + r) * VP + zkt * 16 + lm] = 0;
    }
    __syncthreads();

    // O[16q][64d] = P * V^T over 5 of 6 32-key chunks
    int jclo = wave >> 1;
    f32x4 o[4];
#pragma unroll
    for (int n = 0; n < 4; ++n) o[n] = (f32x4){0.f, 0.f, 0.f, 0.f};
#pragma unroll
    for (int jc2 = 0; jc2 < 5; ++jc2) {
        int jc = jclo + jc2;
        bf16x8 pf = *(const bf16x8*)(Pb + lm * VP + jc * 32 + quad * 8);
#pragma unroll
        for (int n = 0; n < 4; ++n) {
            bf16x8 vf = *(const bf16x8*)(Vt + (n * 16 + lm) * VP + jc * 32 + quad * 8);
            o[n] = __builtin_amdgcn_mfma_f32_16x16x32_bf16(pf, vf, o[n], 0, 0, 0);
        }
    }

    float inv[4];
#pragma unroll
    for (int r = 0; r < 4; ++r) inv[r] = 1.0f / sum[r];
#pragma unroll
    for (int n = 0; n < 4; ++n)
#pragma unroll
        for (int r = 0; r < 4; ++r) {
            int orow = q0 + wave * 16 + quad * 4 + r;
            size_t oidx = ((size_t)(b * 1024 + orow)) * 1024 + h * 64 + n * 16 + lm;
            Og[oidx] = f2b(o[n][r] * inv[r]);
        }
}

// ---- proj GEMM: out[M,N] = attn[M,K] * w2b[N,K]^T + b2, f32 out ----
__global__ void __launch_bounds__(256) gemm_proj(
    const unsigned short* __restrict__ A,   // attn [8192,1024] bf16
    const unsigned short* __restrict__ W,   // w2b [1024,1024] bf16
    const float* __restrict__ bias,         // [1024] f32
    float* __restrict__ Out)                // [8192,1024] f32
{
    const int K = 1024;
    int n0 = blockIdx.x * BN;
    int m0 = blockIdx.y * BM;
    int tid = threadIdx.x;
    int wave = tid >> 6, lane = tid & 63;
    int lm = lane & 15, quad = lane >> 4;
    int mblk = (wave & 1) * 64, nblk = (wave >> 1) * 64;

    __shared__ unsigned short As[BM * BK];
    __shared__ unsigned short Bs[BN * BK];

    int drow = lane >> 3;
    int gcc  = (lane & 7) ^ drow;
    const unsigned short* ga[4]; const unsigned short* gb[4];
    unsigned short *la[4], *lb[4];
#pragma unroll
    for (int p = 0; p < 4; ++p) {
        int r = wave * 32 + p * 8 + drow;
        ga[p] = A + (size_t)(m0 + r) * K + gcc * 8;
        gb[p] = W + (size_t)(n0 + r) * K + gcc * 8;
        la[p] = As + (wave * 32 + p * 8) * 64;
        lb[p] = Bs + (wave * 32 + p * 8) * 64;
    }
    int lm7 = lm & 7;

    f32x4 acc[4][4];
#pragma unroll
    for (int i = 0; i < 4; ++i)
#pragma unroll
        for (int j = 0; j < 4; ++j)
            acc[i][j] = (f32x4){0.f, 0.f, 0.f, 0.f};

    for (int k0 = 0; k0 < K; k0 += BK) {
        __syncthreads();
#pragma unroll
        for (int p = 0; p < 4; ++p) gld16(ga[p] + k0, la[p]);
#pragma unroll
        for (int p = 0; p < 4; ++p) gld16(gb[p] + k0, lb[p]);
        __syncthreads();
        bf16x8 af[4][2], bfr[4][2];
#pragma unroll
        for (int i = 0; i < 4; ++i)
#pragma unroll
            for (int hhh = 0; hhh < 2; ++hhh)
                af[i][hhh] = *(const bf16x8*)(As + (mblk + i * 16 + lm) * 64 +
                                              (((hhh * 4 + quad) ^ lm7) << 3));
#pragma unroll
        for (int j = 0; j < 4; ++j)
#pragma unroll
            for (int hhh = 0; hhh < 2; ++hhh)
                bfr[j][hhh] = *(const bf16x8*)(Bs + (nblk + j * 16 + lm) * 64 +
                                               (((hhh * 4 + quad) ^ lm7) << 3));
#pragma unroll
        for (int i = 0; i < 4; ++i)
#pragma unroll
            for (int j = 0; j < 4; ++j) {
                acc[i][j] = __builtin_amdgcn_mfma_f32_16x16x32_bf16(af[i][0], bfr[j][0], acc[i][j], 0, 0, 0);
                acc[i][j] = __builtin_amdgcn_mfma_f32_16x16x32_bf16(af[i][1], bfr[j][1], acc[i][j], 0, 0, 0);
            }
    }

#pragma unroll
    for (int j = 0; j < 4; ++j) {
        int n = n0 + nblk + j * 16 + lm;
        float bv = bias[n];
#pragma unroll
        for (int i = 0; i < 4; ++i) {
#pragma unroll
            for (int r = 0; r < 4; ++r) {
                int m = m0 + mblk + i * 16 + quad * 4 + r;
                Out[(size_t)m * 1024 + n] = acc[i][j][r] + bv;
            }
        }
    }
}

extern "C" void kernel_launch(void* const* d_in, const int* in_sizes, int n_in,
                              void* d_out, int out_size, void* d_ws, size_t ws_size,
                              hipStream_t stream) {
    const float* x  = (const float*)d_in[0];  // [8,1024,1024] f32
    const float* w1 = (const float*)d_in[1];  // [3072,1024] f32
    const float* b1 = (const float*)d_in[2];  // [3072] f32
    const float* w2 = (const float*)d_in[3];  // [1024,1024] f32
    const float* b2 = (const float*)d_in[4];  // [1024] f32
    float* out = (float*)d_out;               // [8192,1024] f32

    // ws (56 MiB peak):
    //  [0,16Mi)   xb  -> overlaid by attn after gemm_qkv
    //  [16,22Mi)  w1b -> dead after gemm_qkv
    //  [22,24Mi)  w2b
    //  [24,40Mi)  q   [40,56Mi) k
    //  v lives in d_out's first 16 MiB (dead before gemm_proj writes out)
    char* ws = (char*)d_ws;
    const size_t MB = 1024 * 1024;
    unsigned short* xb   = (unsigned short*)(ws);
    unsigned short* w1b  = (unsigned short*)(ws + 16 * MB);
    unsigned short* w2b  = (unsigned short*)(ws + 22 * MB);
    unsigned short* q    = (unsigned short*)(ws + 24 * MB);
    unsigned short* k    = (unsigned short*)(ws + 40 * MB);
    unsigned short* v    = (unsigned short*)d_out;
    unsigned short* attn = (unsigned short*)(ws);

    dim3 blk(256);
    cast_inputs<<<1536, blk, 0, stream>>>(
        (const float4*)x, (const float4*)w1, (const float4*)w2,
        (uint4*)xb, (uint4*)w1b, (uint4*)w2b);
    gemm_qkv<<<dim3(24, 64), blk, 0, stream>>>(xb, w1b, b1, q, k, v);
    attn_local<<<dim3(2048), blk, 0, stream>>>(q, k, v, attn);
    gemm_proj<<<dim3(8, 64), blk, 0, stream>>>(attn, w2b, b2, out);
}